// Round 1
// baseline (519.891 us; speedup 1.0000x reference)
//
#include <hip/hip_runtime.h>

// Bayer mosaic channel selection.
// img: [B=8, C=3, H=2048, W=2048] fp32, out: [B, H, W] fp32
//   (i+j) even -> ch1 ; i even & (i+j) odd -> ch2 ; else -> ch0
// Per-row pattern over j: even row = [ch1, ch2, ch1, ch2, ...]
//                         odd  row = [ch0, ch1, ch0, ch1, ...]
// So each float4 of output needs float4 loads from exactly two channel rows
// at the same (i, j) offset, combined as {A.x, B.y, A.z, B.w}.

#define BAYER_B 8
#define BAYER_H 2048
#define BAYER_W 2048
#define LOG2_W 11
#define LOG2_H 11

__global__ __launch_bounds__(256) void bayer_kernel(const float* __restrict__ img,
                                                    float* __restrict__ out) {
    // each thread produces 4 consecutive output floats
    const size_t tid = (size_t)blockIdx.x * blockDim.x + threadIdx.x;
    const size_t idx = tid << 2;                 // flat output element index

    const int j = (int)(idx & (BAYER_W - 1));    // column (multiple of 4)
    const size_t rest = idx >> LOG2_W;
    const int i = (int)(rest & (BAYER_H - 1));   // row
    const int b = (int)(rest >> LOG2_H);         // batch

    // channel feeding even-j lanes (A) and odd-j lanes (B) of this row
    const int rowOdd = i & 1;
    const int cA = rowOdd ? 0 : 1;
    const int cB = rowOdd ? 1 : 2;

    const size_t plane = (size_t)BAYER_H * BAYER_W;
    const size_t rowBase = (size_t)i * BAYER_W + j;
    const size_t batchBase = (size_t)b * 3 * plane;

    const float4 a = *(const float4*)(img + batchBase + (size_t)cA * plane + rowBase);
    const float4 c = *(const float4*)(img + batchBase + (size_t)cB * plane + rowBase);

    const float4 o = make_float4(a.x, c.y, a.z, c.w);
    *(float4*)(out + idx) = o;
}

extern "C" void kernel_launch(void* const* d_in, const int* in_sizes, int n_in,
                              void* d_out, int out_size, void* d_ws, size_t ws_size,
                              hipStream_t stream) {
    const float* img = (const float*)d_in[0];
    float* out = (float*)d_out;

    const int total_vec4 = (BAYER_B * BAYER_H * BAYER_W) / 4;  // 8,388,608
    const int threads = 256;
    const int blocks = total_vec4 / threads;                   // 32,768

    bayer_kernel<<<blocks, threads, 0, stream>>>(img, out);
}

// Round 2
// 516.141 us; speedup vs baseline: 1.0073x; 1.0073x over previous
//
#include <hip/hip_runtime.h>

// Bayer mosaic channel selection.
// img: [B=8, C=3, H=2048, W=2048] fp32, out: [B, H, W] fp32
//   even row: [ch1, ch2, ch1, ch2, ...]
//   odd  row: [ch0, ch1, ch0, ch1, ...]
// Each output float4 = {A.x, B.y, A.z, B.w} from float4 loads of two channel
// rows at the same (i,j). Memory-bound: floor = 256 MiB read + 128 MiB write
// (discarded components share cache lines -> unavoidable) ~= 60 us @ 6.4 TB/s.
//
// Each thread handles 4 float4s strided by 2 batches: (i,j,cA,cB) computed
// once; only the batch offset advances. 8 independent loads in flight per
// thread (MLP), nontemporal hints (streaming, zero reuse).

#define BAYER_H 2048
#define BAYER_W 2048
#define PLANE ((size_t)BAYER_H * BAYER_W)   // 4,194,304 elements
#define LOG2_W 11
#define LOG2_H 11
#define UNROLL 4

typedef float v4f __attribute__((ext_vector_type(4)));

__global__ __launch_bounds__(256) void bayer_kernel(const float* __restrict__ img,
                                                    float* __restrict__ out) {
    const size_t tid = (size_t)blockIdx.x * blockDim.x + threadIdx.x;
    const size_t idx = tid << 2;                 // output element index, t=0

    const int j = (int)(idx & (BAYER_W - 1));
    const size_t rest = idx >> LOG2_W;
    const int i = (int)(rest & (BAYER_H - 1));
    const int b0 = (int)(rest >> LOG2_H);        // 0 or 1

    const int rowOdd = i & 1;
    const int cA = rowOdd ? 0 : 1;               // feeds even-j lanes (x, z)
    const int cB = rowOdd ? 1 : 2;               // feeds odd-j lanes  (y, w)

    const size_t rowBase = (size_t)i * BAYER_W + j;
    const size_t aOff = (size_t)cA * PLANE + rowBase;
    const size_t bOff = (size_t)cB * PLANE + rowBase;

    const size_t inBatchStride  = 2 * 3 * PLANE; // advance 2 batches
    const size_t outBatchStride = 2 * PLANE;

    size_t base  = (size_t)b0 * 3 * PLANE;
    size_t obase = (size_t)b0 * PLANE + rowBase;

    v4f a[UNROLL], c[UNROLL];
#pragma unroll
    for (int t = 0; t < UNROLL; ++t) {
        a[t] = __builtin_nontemporal_load((const v4f*)(img + base + aOff));
        c[t] = __builtin_nontemporal_load((const v4f*)(img + base + bOff));
        base += inBatchStride;
    }
#pragma unroll
    for (int t = 0; t < UNROLL; ++t) {
        v4f o = {a[t][0], c[t][1], a[t][2], c[t][3]};
        __builtin_nontemporal_store(o, (v4f*)(out + obase));
        obase += outBatchStride;
    }
}

extern "C" void kernel_launch(void* const* d_in, const int* in_sizes, int n_in,
                              void* d_out, int out_size, void* d_ws, size_t ws_size,
                              hipStream_t stream) {
    const float* img = (const float*)d_in[0];
    float* out = (float*)d_out;

    // total output float4s = 8*2048*2048/4 = 8,388,608; /UNROLL(4) = 2,097,152 threads
    const int threads = 256;
    const int blocks = 2097152 / threads;        // 8192
    bayer_kernel<<<blocks, threads, 0, stream>>>(img, out);
}